// Round 6
// baseline (569.336 us; speedup 1.0000x reference)
//
#include <hip/hip_runtime.h>
#include <stdint.h>
#include <stddef.h>

#define NN 100000
#define NE 1600000
#define DD 32
#define NCAND 1024
#define HSIZE 65536
#define SORTN 4096
#define SCAN_B 1024
#define NB ((NN + SCAN_B - 1) / SCAN_B)   // 98 scan blocks
#define NTB 128                            // build block size
#define KCAP 48                            // padded slots/row (Poisson(16): P(d>48)~1e-11)
#define OVFCAP 1024

// capacity for per-stage packed lists (mean + huge margin)
#define CAP1 832000
#define CAP2 432000
#define CAP3 240000

// ---------------- JAX threefry2x32 (20 rounds) ----------------
__host__ __device__ inline void tf2x32(uint32_t k0, uint32_t k1, uint32_t x0, uint32_t x1,
                                       uint32_t& o0, uint32_t& o1) {
  uint32_t ks2 = k0 ^ k1 ^ 0x1BD11BDAu;
  uint32_t v0 = x0 + k0, v1 = x1 + k1;
#define TFR(r) { v0 += v1; v1 = (v1 << (r)) | (v1 >> (32 - (r))); v1 ^= v0; }
  TFR(13) TFR(15) TFR(26) TFR(6)   v0 += k1;  v1 += ks2 + 1u;
  TFR(17) TFR(29) TFR(16) TFR(24)  v0 += ks2; v1 += k0 + 2u;
  TFR(13) TFR(15) TFR(26) TFR(6)   v0 += k0;  v1 += k1 + 3u;
  TFR(17) TFR(29) TFR(16) TFR(24)  v0 += k1;  v1 += ks2 + 4u;
  TFR(13) TFR(15) TFR(26) TFR(6)   v0 += ks2; v1 += k0 + 5u;
#undef TFR
  o0 = v0; o1 = v1;
}

__device__ __forceinline__ uint32_t jax_bits32(uint32_t k0, uint32_t k1, uint32_t i) {
  uint32_t o0, o1;
  tf2x32(k0, k1, 0u, i, o0, o1);
  return o0 ^ o1;
}

__device__ __forceinline__ float bits_to_uniform(uint32_t b) {
  return __fsub_rn(__uint_as_float((b >> 9) | 0x3f800000u), 1.0f);
}

// numpy-pairwise sum of 32 floats
__device__ __forceinline__ float pairwise32(const float* x) {
  float r[8];
#pragma unroll
  for (int j = 0; j < 8; ++j) r[j] = x[j];
#pragma unroll
  for (int b = 8; b < 32; b += 8)
#pragma unroll
    for (int j = 0; j < 8; ++j) r[j] = __fadd_rn(r[j], x[b + j]);
  float a01 = __fadd_rn(r[0], r[1]), a23 = __fadd_rn(r[2], r[3]);
  float a45 = __fadd_rn(r[4], r[5]), a67 = __fadd_rn(r[6], r[7]);
  return __fadd_rn(__fadd_rn(a01, a23), __fadd_rn(a45, a67));
}

// ---------------- kernels ----------------

// fused: threefry levels + packed per-row per-stage counts (u64 atomic; returned
// old low field = seq) + scattered 8B payload {(eid<<2)|lv, col} into padded rows.
__global__ void k_fused(const int* __restrict__ rows, const int* __restrict__ cols,
                        uint32_t k00, uint32_t k01, uint32_t k10, uint32_t k11,
                        uint32_t k20, uint32_t k21,
                        unsigned long long* __restrict__ pcnt, int2* __restrict__ pkPad,
                        int4* __restrict__ ovfBuf, int* __restrict__ ovfCnt) {
  int e = blockIdx.x * blockDim.x + threadIdx.x;
  if (e >= NE) return;
  float u0 = bits_to_uniform(jax_bits32(k00, k01, (uint32_t)e));
  float u1 = bits_to_uniform(jax_bits32(k10, k11, (uint32_t)e));
  float u2 = bits_to_uniform(jax_bits32(k20, k21, (uint32_t)e));
  float kp0 = floorf(__fadd_rn(u0, 0.5f));
  float kp1 = floorf(__fadd_rn(u1, 0.25f));
  float kp2 = floorf(__fadd_rn(u2, 0.125f));
  int lv = 0;
  if (kp0 != 0.0f) { lv = 1; if (kp1 != 0.0f) { lv = 2; if (kp2 != 0.0f) lv = 3; } }
  int c = cols[e];
  int r = rows[e];
  unsigned long long add = 1ull;
  if (lv >= 1) add |= 1ull << 16;
  if (lv >= 2) add |= 1ull << 32;
  if (lv >= 3) add |= 1ull << 48;
  unsigned long long old = atomicAdd(&pcnt[r], add);
  uint32_t seq = (uint32_t)(old & 0xFFFFull);
  int x = (e << 2) | lv;
  if (seq < KCAP) {
    pkPad[(size_t)r * KCAP + seq] = make_int2(x, c);
  } else {
    int q = atomicAdd(ovfCnt, 1);
    if (q < OVFCAP) ovfBuf[q] = make_int4(x, c, r, 0);
  }
}

// multi-array exclusive scan over packed 16-bit fields: grid (NB, 4)
__global__ void k_scan1(const unsigned long long* __restrict__ pcnt, int* __restrict__ rpAll,
                        int* __restrict__ bsumAll) {
  __shared__ int s[SCAN_B];
  int a = blockIdx.y;
  int* rp = rpAll + (size_t)a * (NN + 1);
  int gid = blockIdx.x * SCAN_B + threadIdx.x;
  int v = (gid < NN) ? (int)((pcnt[gid] >> (16 * a)) & 0xFFFFull) : 0;
  s[threadIdx.x] = v;
  __syncthreads();
  for (int off = 1; off < SCAN_B; off <<= 1) {
    int t = (threadIdx.x >= off) ? s[threadIdx.x - off] : 0;
    __syncthreads();
    s[threadIdx.x] += t;
    __syncthreads();
  }
  if (gid < NN) rp[gid] = s[threadIdx.x] - v;  // exclusive
  if (threadIdx.x == SCAN_B - 1) bsumAll[a * 128 + blockIdx.x] = s[threadIdx.x];
}

__global__ void k_scan2(int* __restrict__ bsumAll) {
  __shared__ int s[128];
  int* bsum = bsumAll + blockIdx.x * 128;
  int t = threadIdx.x;
  int v = (t < NB) ? bsum[t] : 0;
  s[t] = v;
  __syncthreads();
  for (int off = 1; off < 128; off <<= 1) {
    int x = (t >= off) ? s[t - off] : 0;
    __syncthreads();
    s[t] += x;
    __syncthreads();
  }
  if (t < NB) bsum[t] = s[t] - v;  // exclusive
}

__global__ void k_scan3(int* __restrict__ rpAll, const int* __restrict__ bsumAll,
                        const unsigned long long* __restrict__ pcnt) {
  int a = blockIdx.y;
  int* rp = rpAll + (size_t)a * (NN + 1);
  int gid = blockIdx.x * SCAN_B + threadIdx.x;
  if (gid < NN) {
    int v = rp[gid] + bsumAll[a * 128 + blockIdx.x];
    rp[gid] = v;
    if (gid == NN - 1) rp[NN] = v + (int)((pcnt[gid] >> (16 * a)) & 0xFFFFull);
  }
}

// per-row: LDS sort 4B keys ((eid<<2|lv)<<6)|i, gather adj, emit 4 stage lists + orders
__global__ __launch_bounds__(NTB) void k_build4(
    const unsigned long long* __restrict__ pcnt, const int* __restrict__ rpAll,
    const int2* __restrict__ pkPad, const float* __restrict__ adj,
    const int4* __restrict__ ovfBuf, const int* __restrict__ ovfCnt,
    int2* __restrict__ pk0, int2* __restrict__ pk1,
    int2* __restrict__ pk2, int2* __restrict__ pk3,
    float* __restrict__ order0, float* __restrict__ order1, float* __restrict__ order2) {
  __shared__ uint32_t K[KCAP * NTB];  // transposed: K[i*NTB+t]
  int t = threadIdx.x;
  int r = blockIdx.x * NTB + t;
  if (r >= NN) return;  // no __syncthreads below; LDS column is thread-private
  int d = (int)(pcnt[r] & 0xFFFFull);
  const int* rp0 = rpAll;
  const int* rp1 = rpAll + (NN + 1);
  const int* rp2 = rpAll + 2 * (NN + 1);
  const int* rp3 = rpAll + 3 * (NN + 1);
  int p0 = rp0[r], p1 = rp1[r], p2 = rp2[r], p3 = rp3[r];
  float o0 = 0.0f, o1 = 0.0f, o2 = 0.0f;
  if (d <= KCAP) {
    const int2* src = pkPad + (size_t)r * KCAP;
    for (int i = 0; i < d; ++i)
      K[i * NTB + t] = ((uint32_t)src[i].x << 6) | (uint32_t)i;  // (eid<<2|lv)<<6|i, 29b
    for (int i = 1; i < d; ++i) {
      uint32_t key = K[i * NTB + t];
      int j = i - 1;
      while (j >= 0) {
        uint32_t kj = K[j * NTB + t];
        if (kj <= key) break;
        K[(j + 1) * NTB + t] = kj;
        --j;
      }
      K[(j + 1) * NTB + t] = key;
    }
    for (int i = 0; i < d; ++i) {
      uint32_t key = K[i * NTB + t];
      int idx = (int)(key & 63u);
      int lv = (int)((key >> 6) & 3u);
      int e = (int)(key >> 8);
      int c = src[idx].y;       // L1-hot re-read
      float a = adj[e];         // gather, L2/L3-hot (6.4 MB array)
      int2 pkv = make_int2(c, __float_as_int(a));
      o0 = __fadd_rn(o0, a);
      pk0[p0++] = pkv;
      if (lv >= 1) {
        o1 = __fadd_rn(o1, a);
        pk1[p1++] = pkv;
        if (lv >= 2) {
          o2 = __fadd_rn(o2, a);
          pk2[p2++] = pkv;
          if (lv >= 3) pk3[p3++] = pkv;
        }
      }
    }
  } else {
    // effectively-never overflow path (d>KCAP): merge padded + overflow capture
    int2 tmp[96];
    int dd = 0;
    for (int i = 0; i < KCAP; ++i) tmp[dd++] = pkPad[(size_t)r * KCAP + i];
    int n = *ovfCnt; if (n > OVFCAP) n = OVFCAP;
    for (int q = 0; q < n; ++q) {
      int4 p = ovfBuf[q];
      if (p.z == r && dd < 96) tmp[dd++] = make_int2(p.x, p.y);
    }
    for (int i = 1; i < dd; ++i) {
      int2 key = tmp[i];
      int j = i - 1;
      while (j >= 0 && tmp[j].x > key.x) { tmp[j + 1] = tmp[j]; --j; }
      tmp[j + 1] = key;
    }
    for (int i = 0; i < dd; ++i) {
      int lv = tmp[i].x & 3;
      int e = tmp[i].x >> 2;
      int c = tmp[i].y;
      float a = adj[e];
      int2 pkv = make_int2(c, __float_as_int(a));
      o0 = __fadd_rn(o0, a);
      pk0[p0++] = pkv;
      if (lv >= 1) {
        o1 = __fadd_rn(o1, a);
        pk1[p1++] = pkv;
        if (lv >= 2) {
          o2 = __fadd_rn(o2, a);
          pk2[p2++] = pkv;
          if (lv >= 3) pk3[p3++] = pkv;
        }
      }
    }
  }
  order0[r] = o0; order1[r] = o1; order2[r] = o2;
}

// fst_emb = spmm(adj, embeds) - embeds
__global__ void k_emb0(const int* __restrict__ rp, const int2* __restrict__ pk,
                       const float* __restrict__ embeds, float* __restrict__ e0) {
  int tid = blockIdx.x * blockDim.x + threadIdx.x;
  int r = tid >> 5, d = tid & 31;
  if (r >= NN) return;
  int s = rp[r], t = rp[r + 1];
  float acc = 0.0f;
  for (int base = s; base < t; base += 32) {
    int idx = base + d;
    int2 p = (idx < t) ? pk[idx] : make_int2(0, 0);
    int m = t - base; if (m > 32) m = 32;
    for (int j = 0; j < m; ++j) {
      int c = __shfl(p.x, j, 32);
      int ab = __shfl(p.y, j, 32);
      float x = embeds[(size_t)c * DD + d];
      acc = __fadd_rn(acc, __fmul_rn(__int_as_float(ab), x));
    }
  }
  e0[(size_t)r * DD + d] = __fsub_rn(acc, embeds[(size_t)r * DD + d]);
}

// emb_next = spmm(stage vals, emb_cur) - emb_cur - order*emb_cur
// mode: 1 = S = ec + o (init), write next; 2 = S += o, write next; 3 = S += o only
__global__ void k_emb_step(const int* __restrict__ rp, const int2* __restrict__ pk,
                           const float* __restrict__ ord, const float* __restrict__ ecur,
                           float* __restrict__ enext, float* __restrict__ esum, int mode) {
  int tid = blockIdx.x * blockDim.x + threadIdx.x;
  int r = tid >> 5, d = tid & 31;
  if (r >= NN) return;
  int s = rp[r], t = rp[r + 1];
  float acc = 0.0f;
  for (int base = s; base < t; base += 32) {
    int idx = base + d;
    int2 p = (idx < t) ? pk[idx] : make_int2(0, 0);
    int m = t - base; if (m > 32) m = 32;
    for (int j = 0; j < m; ++j) {
      int c = __shfl(p.x, j, 32);
      int ab = __shfl(p.y, j, 32);
      float x = ecur[(size_t)c * DD + d];
      acc = __fadd_rn(acc, __fmul_rn(__int_as_float(ab), x));
    }
  }
  size_t idx = (size_t)r * DD + d;
  float ec = ecur[idx];
  float o = __fsub_rn(__fsub_rn(acc, ec), __fmul_rn(ord[r], ec));
  if (mode != 3) enext[idx] = o;
  if (mode == 1) esum[idx] = __fadd_rn(ec, o);
  else esum[idx] = __fadd_rn(esum[idx], o);
}

// num_next = spmm(stage vals, num_cur) - num_cur - order
__global__ void k_num_step(const int* __restrict__ rp, const int2* __restrict__ pk,
                           const float* __restrict__ ord, const float* __restrict__ ncur,
                           float* __restrict__ nnext, float* __restrict__ nsum, int mode) {
  int r = blockIdx.x * blockDim.x + threadIdx.x;
  if (r >= NN) return;
  int s = rp[r], t = rp[r + 1];
  float acc = 0.0f;
  for (int k = s; k < t; ++k) {
    int2 p = pk[k];
    acc = __fadd_rn(acc, __fmul_rn(__int_as_float(p.y), ncur[p.x]));
  }
  float nc = ncur[r];
  float o = __fsub_rn(__fsub_rn(acc, nc), ord[r]);
  if (mode != 3) nnext[r] = o;
  if (mode == 1) nsum[r] = __fadd_rn(nc, o);
  else nsum[r] = __fadd_rn(nsum[r], o);
}

__global__ void k_final(const float* __restrict__ embeds, const float* __restrict__ emb_sum,
                        const float* __restrict__ num_sum, uint32_t gk0, uint32_t gk1,
                        float* __restrict__ out_scores, int* __restrict__ hist) {
  int r = blockIdx.x * blockDim.x + threadIdx.x;
  if (r >= NN) return;
  float denom = __fadd_rn(num_sum[r], 1e-8f);
  float sub[DD], em[DD], pr[DD];
  const float4* ps = (const float4*)(emb_sum + (size_t)r * DD);
  const float4* pe = (const float4*)(embeds + (size_t)r * DD);
#pragma unroll
  for (int j = 0; j < 8; ++j) {
    float4 a = ps[j], b = pe[j];
    sub[4 * j + 0] = __fdiv_rn(a.x, denom); sub[4 * j + 1] = __fdiv_rn(a.y, denom);
    sub[4 * j + 2] = __fdiv_rn(a.z, denom); sub[4 * j + 3] = __fdiv_rn(a.w, denom);
    em[4 * j + 0] = b.x; em[4 * j + 1] = b.y; em[4 * j + 2] = b.z; em[4 * j + 3] = b.w;
  }
#pragma unroll
  for (int d = 0; d < DD; ++d) pr[d] = __fmul_rn(sub[d], sub[d]);
  float n1 = fmaxf(__fsqrt_rn(pairwise32(pr)), 1e-12f);
#pragma unroll
  for (int d = 0; d < DD; ++d) pr[d] = __fmul_rn(em[d], em[d]);
  float n2 = fmaxf(__fsqrt_rn(pairwise32(pr)), 1e-12f);
#pragma unroll
  for (int d = 0; d < DD; ++d)
    pr[d] = __fmul_rn(__fdiv_rn(sub[d], n1), __fdiv_rn(em[d], n2));
  float dot = pairwise32(pr);
  float u = bits_to_uniform(jax_bits32(gk0, gk1, (uint32_t)r));
  float l1 = (float)log((double)u);
  float w = -l1;
  float l2 = (float)log((double)w);
  float g = -l2;
  float score = __fadd_rn(dot, g);
  out_scores[r] = score;
  uint32_t kb = __float_as_uint(score);
  kb = (kb & 0x80000000u) ? ~kb : (kb | 0x80000000u);
  atomicAdd(&hist[kb >> 16], 1);
}

__global__ void k_cutoff(const int* __restrict__ hist, int* __restrict__ cutoff) {
  __shared__ int psum[1024];
  int t = threadIdx.x;
  int base = HSIZE - (t + 1) * 64;
  int own = 0;
  for (int i = 0; i < 64; ++i) own += hist[base + i];
  psum[t] = own;
  __syncthreads();
  for (int off = 1; off < 1024; off <<= 1) {
    int v = (t >= off) ? psum[t - off] : 0;
    __syncthreads();
    psum[t] += v;
    __syncthreads();
  }
  int incl = psum[t];
  int prev = incl - own;
  if (incl >= NCAND && prev < NCAND) {
    int c = prev;
    int b = HSIZE - t * 64 - 1;
    while (b >= base) {
      c += hist[b];
      if (c >= NCAND) break;
      --b;
    }
    *cutoff = b;
  }
}

__global__ void k_collect(const float* __restrict__ scores, const int* __restrict__ cutoff,
                          unsigned long long* __restrict__ buf, int* __restrict__ cnt2) {
  int r = blockIdx.x * blockDim.x + threadIdx.x;
  if (r >= NN) return;
  uint32_t kb = __float_as_uint(scores[r]);
  kb = (kb & 0x80000000u) ? ~kb : (kb | 0x80000000u);
  if ((int)(kb >> 16) >= *cutoff) {
    int p = atomicAdd(cnt2, 1);
    if (p < SORTN)
      buf[p] = ((unsigned long long)kb << 32) | (uint32_t)(~(uint32_t)r);
  }
}

__global__ __launch_bounds__(1024) void k_sort(const unsigned long long* __restrict__ buf,
                                               const int* __restrict__ cnt2,
                                               float* __restrict__ out_cand) {
  __shared__ unsigned long long s[SORTN];
  int m = *cnt2;
  if (m > SORTN) m = SORTN;
  for (int i = threadIdx.x; i < SORTN; i += 1024) s[i] = (i < m) ? buf[i] : 0ull;
  __syncthreads();
  for (int k = 2; k <= SORTN; k <<= 1) {
    for (int j = k >> 1; j > 0; j >>= 1) {
      for (int i = threadIdx.x; i < SORTN; i += 1024) {
        int ixj = i ^ j;
        if (ixj > i) {
          unsigned long long a = s[i], b = s[ixj];
          bool desc = ((i & k) == 0);
          if (desc ? (a < b) : (a > b)) { s[i] = b; s[ixj] = a; }
        }
      }
      __syncthreads();
    }
  }
  for (int i = threadIdx.x; i < NCAND; i += 1024) {
    uint32_t idx = ~((uint32_t)(s[i] & 0xffffffffull));
    out_cand[i] = (float)idx;
  }
}

// ---------------- host ----------------
extern "C" void kernel_launch(void* const* d_in, const int* in_sizes, int n_in,
                              void* d_out, int out_size, void* d_ws, size_t ws_size,
                              hipStream_t stream) {
  const int* rows = (const int*)d_in[0];
  const int* cols = rows + NE;
  const float* adj = (const float*)d_in[1];
  const float* embeds = (const float*)d_in[2];
  float* out = (float*)d_out;

  char* p = (char*)d_ws;
  auto alloc = [&](size_t bytes) {
    char* q = p;
    p += (bytes + 255) & ~(size_t)255;
    return q;
  };
  // single contiguous zero region: pcnt(u64 x NN) | hist | cnt2(2) | ovfCnt(1)
  size_t zero_bytes = (size_t)NN * 8 + (size_t)HSIZE * 4 + 256;
  char* zero_base = (char*)alloc(zero_bytes);
  unsigned long long* pcnt = (unsigned long long*)zero_base;
  int* hist = (int*)(pcnt + NN);
  int* cnt2 = hist + HSIZE;   // [0]=collect count, [1]=cutoff bin
  int* ovfCnt = cnt2 + 2;

  int* rpAll = (int*)alloc((size_t)4 * (NN + 1) * 4);
  int* bsumAll = (int*)alloc(4 * 128 * 4);
  // pkPad (38.4 MB) dead after build4; embA/embB/embS (3 x 12.8 MB) overlay it.
  char* padBase = (char*)alloc((size_t)NN * KCAP * 8);
  int2* pkPad = (int2*)padBase;
  float* embA = (float*)padBase;                             // 12.8 MB
  float* embB = (float*)(padBase + (size_t)NN * DD * 4);     // 12.8 MB
  float* embS = (float*)(padBase + (size_t)2 * NN * DD * 4); // 12.8 MB
  int2* pk0 = (int2*)alloc((size_t)NE * 8);
  int2* pk1 = (int2*)alloc((size_t)CAP1 * 8);
  int2* pk2 = (int2*)alloc((size_t)CAP2 * 8);
  int2* pk3 = (int2*)alloc((size_t)CAP3 * 8);
  int4* ovfBuf = (int4*)alloc((size_t)OVFCAP * 16);
  float* order0 = (float*)alloc(NN * 4);
  float* order1 = (float*)alloc(NN * 4);
  float* order2 = (float*)alloc(NN * 4);
  float* num1 = (float*)alloc(NN * 4);
  float* num2 = (float*)alloc(NN * 4);
  float* numS = (float*)alloc(NN * 4);
  unsigned long long* buf = (unsigned long long*)alloc(SORTN * 8);

  uint32_t dk[3][2];
  for (int i = 0; i < 3; ++i) tf2x32(0u, 42u, 0u, (uint32_t)i, dk[i][0], dk[i][1]);

  hipMemsetAsync(zero_base, 0, zero_bytes, stream);

  k_fused<<<(NE + 255) / 256, 256, 0, stream>>>(
      rows, cols, dk[0][0], dk[0][1], dk[1][0], dk[1][1], dk[2][0], dk[2][1],
      pcnt, pkPad, ovfBuf, ovfCnt);

  dim3 sg(NB, 4);
  k_scan1<<<sg, SCAN_B, 0, stream>>>(pcnt, rpAll, bsumAll);
  k_scan2<<<4, 128, 0, stream>>>(bsumAll);
  k_scan3<<<sg, SCAN_B, 0, stream>>>(rpAll, bsumAll, pcnt);

  k_build4<<<(NN + NTB - 1) / NTB, NTB, 0, stream>>>(pcnt, rpAll, pkPad, adj, ovfBuf,
                                                     ovfCnt, pk0, pk1, pk2, pk3,
                                                     order0, order1, order2);

  const int* rp0 = rpAll;
  const int* rp1 = rpAll + (NN + 1);
  const int* rp2 = rpAll + 2 * (NN + 1);
  const int* rp3 = rpAll + 3 * (NN + 1);

  int gEmb = (NN * 32 + 255) / 256;
  k_emb0<<<gEmb, 256, 0, stream>>>(rp0, pk0, embeds, embA);

  // stage 1: cur=embA -> next=embB, S init
  k_emb_step<<<gEmb, 256, 0, stream>>>(rp1, pk1, order0, embA, embB, embS, 1);
  k_num_step<<<(NN + 255) / 256, 256, 0, stream>>>(rp1, pk1, order0, order0, num1, numS, 1);
  // stage 2: cur=embB -> next=embA, S +=
  k_emb_step<<<gEmb, 256, 0, stream>>>(rp2, pk2, order1, embB, embA, embS, 2);
  k_num_step<<<(NN + 255) / 256, 256, 0, stream>>>(rp2, pk2, order1, num1, num2, numS, 2);
  // stage 3: cur=embA, S += only
  k_emb_step<<<gEmb, 256, 0, stream>>>(rp3, pk3, order2, embA, (float*)nullptr, embS, 3);
  k_num_step<<<(NN + 255) / 256, 256, 0, stream>>>(rp3, pk3, order2, num2, (float*)nullptr,
                                                   numS, 3);

  k_final<<<(NN + 255) / 256, 256, 0, stream>>>(embeds, embS, numS, 0u, 7u, out, hist);
  k_cutoff<<<1, 1024, 0, stream>>>(hist, cnt2 + 1);
  k_collect<<<(NN + 255) / 256, 256, 0, stream>>>(out, cnt2 + 1, buf, cnt2);
  k_sort<<<1, 1024, 0, stream>>>(buf, cnt2, out + NN);
}

// Round 7
// 520.764 us; speedup vs baseline: 1.0933x; 1.0933x over previous
//
#include <hip/hip_runtime.h>
#include <stdint.h>
#include <stddef.h>

#define NN 100000
#define NE 1600000
#define DD 32
#define NCAND 1024
#define HSIZE 65536
#define SORTN 4096
#define SCAN_B 1024
#define NB ((NN + SCAN_B - 1) / SCAN_B)   // 98 blocks per scan array
#define NTB 128                            // k_build2 block size
#define KMAX 64                            // max in-LDS degree (Poisson(16) max ~45)

// capacity for per-stage packed lists (mean + huge margin)
#define CAP1 832000
#define CAP2 432000
#define CAP3 240000

// ---------------- JAX threefry2x32 (20 rounds) ----------------
__host__ __device__ inline void tf2x32(uint32_t k0, uint32_t k1, uint32_t x0, uint32_t x1,
                                       uint32_t& o0, uint32_t& o1) {
  uint32_t ks2 = k0 ^ k1 ^ 0x1BD11BDAu;
  uint32_t v0 = x0 + k0, v1 = x1 + k1;
#define TFR(r) { v0 += v1; v1 = (v1 << (r)) | (v1 >> (32 - (r))); v1 ^= v0; }
  TFR(13) TFR(15) TFR(26) TFR(6)   v0 += k1;  v1 += ks2 + 1u;
  TFR(17) TFR(29) TFR(16) TFR(24)  v0 += ks2; v1 += k0 + 2u;
  TFR(13) TFR(15) TFR(26) TFR(6)   v0 += k0;  v1 += k1 + 3u;
  TFR(17) TFR(29) TFR(16) TFR(24)  v0 += k1;  v1 += ks2 + 4u;
  TFR(13) TFR(15) TFR(26) TFR(6)   v0 += ks2; v1 += k0 + 5u;
#undef TFR
  o0 = v0; o1 = v1;
}

__device__ __forceinline__ uint32_t jax_bits32(uint32_t k0, uint32_t k1, uint32_t i) {
  uint32_t o0, o1;
  tf2x32(k0, k1, 0u, i, o0, o1);
  return o0 ^ o1;
}

__device__ __forceinline__ float bits_to_uniform(uint32_t b) {
  return __fsub_rn(__uint_as_float((b >> 9) | 0x3f800000u), 1.0f);
}

// numpy-pairwise sum of 32 floats
__device__ __forceinline__ float pairwise32(const float* x) {
  float r[8];
#pragma unroll
  for (int j = 0; j < 8; ++j) r[j] = x[j];
#pragma unroll
  for (int b = 8; b < 32; b += 8)
#pragma unroll
    for (int j = 0; j < 8; ++j) r[j] = __fadd_rn(r[j], x[b + j]);
  float a01 = __fadd_rn(r[0], r[1]), a23 = __fadd_rn(r[2], r[3]);
  float a45 = __fadd_rn(r[4], r[5]), a67 = __fadd_rn(r[6], r[7]);
  return __fadd_rn(__fadd_rn(a01, a23), __fadd_rn(a45, a67));
}

// ---------------- kernels ----------------

// levels + packed per-row per-stage counts (one u64 atomic, 16-bit fields).
// Returned old low field = per-row sequence number; packed with lv -> lvseq[e].
__global__ void k_level_count(const int* __restrict__ rows,
                              uint32_t k00, uint32_t k01, uint32_t k10, uint32_t k11,
                              uint32_t k20, uint32_t k21,
                              uint32_t* __restrict__ lvseq,
                              unsigned long long* __restrict__ pcnt) {
  int e = blockIdx.x * blockDim.x + threadIdx.x;
  if (e >= NE) return;
  float u0 = bits_to_uniform(jax_bits32(k00, k01, (uint32_t)e));
  float u1 = bits_to_uniform(jax_bits32(k10, k11, (uint32_t)e));
  float u2 = bits_to_uniform(jax_bits32(k20, k21, (uint32_t)e));
  float kp0 = floorf(__fadd_rn(u0, 0.5f));
  float kp1 = floorf(__fadd_rn(u1, 0.25f));
  float kp2 = floorf(__fadd_rn(u2, 0.125f));
  int lv = 0;
  if (kp0 != 0.0f) { lv = 1; if (kp1 != 0.0f) { lv = 2; if (kp2 != 0.0f) lv = 3; } }
  unsigned long long add = 1ull;
  if (lv >= 1) add |= 1ull << 16;
  if (lv >= 2) add |= 1ull << 32;
  if (lv >= 3) add |= 1ull << 48;
  unsigned long long old = atomicAdd(&pcnt[rows[e]], add);
  lvseq[e] = ((uint32_t)lv << 16) | (uint32_t)(old & 0xFFFFull);
}

// multi-array exclusive scan over packed 16-bit fields: grid (NB, 4)
__global__ void k_scan1(const unsigned long long* __restrict__ pcnt, int* __restrict__ rpAll,
                        int* __restrict__ bsumAll) {
  __shared__ int s[SCAN_B];
  int a = blockIdx.y;
  int* rp = rpAll + (size_t)a * (NN + 1);
  int gid = blockIdx.x * SCAN_B + threadIdx.x;
  int v = (gid < NN) ? (int)((pcnt[gid] >> (16 * a)) & 0xFFFFull) : 0;
  s[threadIdx.x] = v;
  __syncthreads();
  for (int off = 1; off < SCAN_B; off <<= 1) {
    int t = (threadIdx.x >= off) ? s[threadIdx.x - off] : 0;
    __syncthreads();
    s[threadIdx.x] += t;
    __syncthreads();
  }
  if (gid < NN) rp[gid] = s[threadIdx.x] - v;  // exclusive
  if (threadIdx.x == SCAN_B - 1) bsumAll[a * 128 + blockIdx.x] = s[threadIdx.x];
}

__global__ void k_scan2(int* __restrict__ bsumAll) {
  __shared__ int s[128];
  int* bsum = bsumAll + blockIdx.x * 128;
  int t = threadIdx.x;
  int v = (t < NB) ? bsum[t] : 0;
  s[t] = v;
  __syncthreads();
  for (int off = 1; off < 128; off <<= 1) {
    int x = (t >= off) ? s[t - off] : 0;
    __syncthreads();
    s[t] += x;
    __syncthreads();
  }
  if (t < NB) bsum[t] = s[t] - v;  // exclusive
}

__global__ void k_scan3(int* __restrict__ rpAll, const int* __restrict__ bsumAll,
                        const unsigned long long* __restrict__ pcnt) {
  int a = blockIdx.y;
  int* rp = rpAll + (size_t)a * (NN + 1);
  int gid = blockIdx.x * SCAN_B + threadIdx.x;
  if (gid < NN) {
    int v = rp[gid] + bsumAll[a * 128 + blockIdx.x];
    rp[gid] = v;
    if (gid == NN - 1) rp[NN] = v + (int)((pcnt[gid] >> (16 * a)) & 0xFFFFull);
  }
}

// edge-parallel: coalesced source reads, one scattered 16B write, no atomics
__global__ void k_scatter(const int* __restrict__ rows, const int* __restrict__ cols,
                          const float* __restrict__ adj, const uint32_t* __restrict__ lvseq,
                          const int* __restrict__ rp0, int4* __restrict__ pkRaw) {
  int e = blockIdx.x * blockDim.x + threadIdx.x;
  if (e >= NE) return;
  int c = cols[e];
  int ab = __float_as_int(adj[e]);
  uint32_t v = lvseq[e];
  int lv = (int)(v >> 16);
  int r = rows[e];
  int pos = rp0[r] + (int)(v & 0xFFFFu);
  pkRaw[pos] = make_int4(c, ab, lv, e);
}

// per-row: LDS insertion sort of packed keys (eid<<6)|i, emit packed stage lists + orders
__global__ __launch_bounds__(NTB) void k_build2(
    const int* __restrict__ rpAll, int4* __restrict__ pkRaw,
    int2* __restrict__ pk0, int2* __restrict__ pk1,
    int2* __restrict__ pk2, int2* __restrict__ pk3,
    float* __restrict__ order0, float* __restrict__ order1, float* __restrict__ order2) {
  __shared__ uint32_t K[KMAX * NTB];  // transposed: K[i*NTB + t], bank = t%32 (2-way, free)
  int t = threadIdx.x;
  int r = blockIdx.x * NTB + t;
  if (r >= NN) return;  // no __syncthreads below; LDS column is thread-private
  const int* rp0 = rpAll;
  const int* rp1 = rpAll + (NN + 1);
  const int* rp2 = rpAll + 2 * (NN + 1);
  const int* rp3 = rpAll + 3 * (NN + 1);
  int s = rp0[r], en = rp0[r + 1];
  int d = en - s;
  int p0 = s, p1 = rp1[r], p2 = rp2[r], p3 = rp3[r];
  float o0 = 0.0f, o1 = 0.0f, o2 = 0.0f;
  if (d <= KMAX) {
    for (int i = 0; i < d; ++i) {
      int4 p = pkRaw[s + i];
      K[i * NTB + t] = ((uint32_t)p.w << 6) | (uint32_t)i;
    }
    for (int i = 1; i < d; ++i) {
      uint32_t key = K[i * NTB + t];
      int j = i - 1;
      while (j >= 0) {
        uint32_t kj = K[j * NTB + t];
        if (kj <= key) break;
        K[(j + 1) * NTB + t] = kj;
        --j;
      }
      K[(j + 1) * NTB + t] = key;
    }
    for (int i = 0; i < d; ++i) {
      int idx = (int)(K[i * NTB + t] & 63u);
      int4 p = pkRaw[s + idx];  // L1-hot re-read
      float a = __int_as_float(p.y);
      int lv = p.z;
      int2 pk = make_int2(p.x, p.y);
      o0 = __fadd_rn(o0, a);
      pk0[p0++] = pk;
      if (lv >= 1) {
        o1 = __fadd_rn(o1, a);
        pk1[p1++] = pk;
        if (lv >= 2) {
          o2 = __fadd_rn(o2, a);
          pk2[p2++] = pk;
          if (lv >= 3) pk3[p3++] = pk;
        }
      }
    }
  } else {
    // effectively-never fallback: global in-place insertion sort by eid
    for (int i = s + 1; i < en; ++i) {
      int4 key = pkRaw[i];
      int j = i - 1;
      while (j >= s && pkRaw[j].w > key.w) { pkRaw[j + 1] = pkRaw[j]; --j; }
      pkRaw[j + 1] = key;
    }
    for (int i = s; i < en; ++i) {
      int4 p = pkRaw[i];
      float a = __int_as_float(p.y);
      int lv = p.z;
      int2 pk = make_int2(p.x, p.y);
      o0 = __fadd_rn(o0, a);
      pk0[p0++] = pk;
      if (lv >= 1) {
        o1 = __fadd_rn(o1, a);
        pk1[p1++] = pk;
        if (lv >= 2) {
          o2 = __fadd_rn(o2, a);
          pk2[p2++] = pk;
          if (lv >= 3) pk3[p3++] = pk;
        }
      }
    }
  }
  order0[r] = o0; order1[r] = o1; order2[r] = o2;
}

// fst_emb = spmm(adj, embeds) - embeds  (write E0 only)
__global__ void k_emb0(const int* __restrict__ rp, const int2* __restrict__ pk,
                       const float* __restrict__ embeds, float* __restrict__ e0) {
  int tid = blockIdx.x * blockDim.x + threadIdx.x;
  int r = tid >> 5, d = tid & 31;
  if (r >= NN) return;
  int s = rp[r], t = rp[r + 1];
  float acc = 0.0f;
  for (int base = s; base < t; base += 32) {
    int idx = base + d;
    int2 p = (idx < t) ? pk[idx] : make_int2(0, 0);
    int m = t - base; if (m > 32) m = 32;
    for (int j = 0; j < m; ++j) {
      int c = __shfl(p.x, j, 32);
      int ab = __shfl(p.y, j, 32);
      float x = embeds[(size_t)c * DD + d];
      acc = __fadd_rn(acc, __fmul_rn(__int_as_float(ab), x));
    }
  }
  e0[(size_t)r * DD + d] = __fsub_rn(acc, embeds[(size_t)r * DD + d]);
}

// FUSED emb+num step:
//   emb_next = spmm(stage vals, emb_cur) - emb_cur - order*emb_cur
//   num_next = spmm(stage vals, num_cur) - num_cur - order   (lane d==0 writes)
// mode: 1 = sums init (= cur + out), write next; 2 = sums +=, write next; 3 = sums += only
__global__ void k_emb_step(const int* __restrict__ rp, const int2* __restrict__ pk,
                           const float* __restrict__ ord, const float* __restrict__ ecur,
                           float* __restrict__ enext, float* __restrict__ esum,
                           const float* __restrict__ ncur, float* __restrict__ nnext,
                           float* __restrict__ nsum, int mode) {
  int tid = blockIdx.x * blockDim.x + threadIdx.x;
  int r = tid >> 5, d = tid & 31;
  if (r >= NN) return;
  int s = rp[r], t = rp[r + 1];
  float acc = 0.0f, accn = 0.0f;
  for (int base = s; base < t; base += 32) {
    int idx = base + d;
    int2 p = (idx < t) ? pk[idx] : make_int2(0, 0);
    int m = t - base; if (m > 32) m = 32;
    for (int j = 0; j < m; ++j) {
      int c = __shfl(p.x, j, 32);
      int ab = __shfl(p.y, j, 32);
      float av = __int_as_float(ab);
      float x = ecur[(size_t)c * DD + d];
      float xn = ncur[c];  // broadcast load (all lanes same address)
      acc = __fadd_rn(acc, __fmul_rn(av, x));
      accn = __fadd_rn(accn, __fmul_rn(av, xn));
    }
  }
  float ordv = ord[r];
  size_t idx = (size_t)r * DD + d;
  float ec = ecur[idx];
  float o = __fsub_rn(__fsub_rn(acc, ec), __fmul_rn(ordv, ec));
  if (mode != 3) enext[idx] = o;
  if (mode == 1) esum[idx] = __fadd_rn(ec, o);
  else esum[idx] = __fadd_rn(esum[idx], o);
  if (d == 0) {
    float nc = ncur[r];
    float on = __fsub_rn(__fsub_rn(accn, nc), ordv);
    if (mode != 3) nnext[r] = on;
    if (mode == 1) nsum[r] = __fadd_rn(nc, on);
    else nsum[r] = __fadd_rn(nsum[r], on);
  }
}

__global__ void k_final(const float* __restrict__ embeds, const float* __restrict__ emb_sum,
                        const float* __restrict__ num_sum, uint32_t gk0, uint32_t gk1,
                        float* __restrict__ out_scores, int* __restrict__ hist) {
  int r = blockIdx.x * blockDim.x + threadIdx.x;
  if (r >= NN) return;
  float denom = __fadd_rn(num_sum[r], 1e-8f);
  float sub[DD], em[DD], pr[DD];
  const float4* ps = (const float4*)(emb_sum + (size_t)r * DD);
  const float4* pe = (const float4*)(embeds + (size_t)r * DD);
#pragma unroll
  for (int j = 0; j < 8; ++j) {
    float4 a = ps[j], b = pe[j];
    sub[4 * j + 0] = __fdiv_rn(a.x, denom); sub[4 * j + 1] = __fdiv_rn(a.y, denom);
    sub[4 * j + 2] = __fdiv_rn(a.z, denom); sub[4 * j + 3] = __fdiv_rn(a.w, denom);
    em[4 * j + 0] = b.x; em[4 * j + 1] = b.y; em[4 * j + 2] = b.z; em[4 * j + 3] = b.w;
  }
#pragma unroll
  for (int d = 0; d < DD; ++d) pr[d] = __fmul_rn(sub[d], sub[d]);
  float n1 = fmaxf(__fsqrt_rn(pairwise32(pr)), 1e-12f);
#pragma unroll
  for (int d = 0; d < DD; ++d) pr[d] = __fmul_rn(em[d], em[d]);
  float n2 = fmaxf(__fsqrt_rn(pairwise32(pr)), 1e-12f);
#pragma unroll
  for (int d = 0; d < DD; ++d)
    pr[d] = __fmul_rn(__fdiv_rn(sub[d], n1), __fdiv_rn(em[d], n2));
  float dot = pairwise32(pr);
  float u = bits_to_uniform(jax_bits32(gk0, gk1, (uint32_t)r));
  float l1 = (float)log((double)u);
  float w = -l1;
  float l2 = (float)log((double)w);
  float g = -l2;
  float score = __fadd_rn(dot, g);
  out_scores[r] = score;
  uint32_t kb = __float_as_uint(score);
  kb = (kb & 0x80000000u) ? ~kb : (kb | 0x80000000u);
  atomicAdd(&hist[kb >> 16], 1);
}

__global__ void k_cutoff(const int* __restrict__ hist, int* __restrict__ cutoff) {
  __shared__ int psum[1024];
  int t = threadIdx.x;
  int base = HSIZE - (t + 1) * 64;
  int own = 0;
  for (int i = 0; i < 64; ++i) own += hist[base + i];
  psum[t] = own;
  __syncthreads();
  for (int off = 1; off < 1024; off <<= 1) {
    int v = (t >= off) ? psum[t - off] : 0;
    __syncthreads();
    psum[t] += v;
    __syncthreads();
  }
  int incl = psum[t];
  int prev = incl - own;
  if (incl >= NCAND && prev < NCAND) {
    int c = prev;
    int b = HSIZE - t * 64 - 1;
    while (b >= base) {
      c += hist[b];
      if (c >= NCAND) break;
      --b;
    }
    *cutoff = b;
  }
}

__global__ void k_collect(const float* __restrict__ scores, const int* __restrict__ cutoff,
                          unsigned long long* __restrict__ buf, int* __restrict__ cnt2) {
  int r = blockIdx.x * blockDim.x + threadIdx.x;
  if (r >= NN) return;
  uint32_t kb = __float_as_uint(scores[r]);
  kb = (kb & 0x80000000u) ? ~kb : (kb | 0x80000000u);
  if ((int)(kb >> 16) >= *cutoff) {
    int p = atomicAdd(cnt2, 1);
    if (p < SORTN)
      buf[p] = ((unsigned long long)kb << 32) | (uint32_t)(~(uint32_t)r);
  }
}

__global__ __launch_bounds__(1024) void k_sort(const unsigned long long* __restrict__ buf,
                                               const int* __restrict__ cnt2,
                                               float* __restrict__ out_cand) {
  __shared__ unsigned long long s[SORTN];
  int m = *cnt2;
  if (m > SORTN) m = SORTN;
  for (int i = threadIdx.x; i < SORTN; i += 1024) s[i] = (i < m) ? buf[i] : 0ull;
  __syncthreads();
  for (int k = 2; k <= SORTN; k <<= 1) {
    for (int j = k >> 1; j > 0; j >>= 1) {
      for (int i = threadIdx.x; i < SORTN; i += 1024) {
        int ixj = i ^ j;
        if (ixj > i) {
          unsigned long long a = s[i], b = s[ixj];
          bool desc = ((i & k) == 0);
          if (desc ? (a < b) : (a > b)) { s[i] = b; s[ixj] = a; }
        }
      }
      __syncthreads();
    }
  }
  for (int i = threadIdx.x; i < NCAND; i += 1024) {
    uint32_t idx = ~((uint32_t)(s[i] & 0xffffffffull));
    out_cand[i] = (float)idx;
  }
}

// ---------------- host ----------------
extern "C" void kernel_launch(void* const* d_in, const int* in_sizes, int n_in,
                              void* d_out, int out_size, void* d_ws, size_t ws_size,
                              hipStream_t stream) {
  const int* rows = (const int*)d_in[0];
  const int* cols = rows + NE;
  const float* adj = (const float*)d_in[1];
  const float* embeds = (const float*)d_in[2];
  float* out = (float*)d_out;

  char* p = (char*)d_ws;
  auto alloc = [&](size_t bytes) {
    char* q = p;
    p += (bytes + 255) & ~(size_t)255;
    return q;
  };
  // single contiguous zero region: pcnt(u64 x NN) | hist | cnt2
  size_t zero_bytes = (size_t)NN * 8 + (size_t)HSIZE * 4 + 256;
  char* zero_base = (char*)alloc(zero_bytes);
  unsigned long long* pcnt = (unsigned long long*)zero_base;
  int* hist = (int*)(pcnt + NN);
  int* cnt2 = hist + HSIZE;  // [0]=collect count, [1]=cutoff bin

  int* rpAll = (int*)alloc((size_t)4 * (NN + 1) * 4);
  int* bsumAll = (int*)alloc(4 * 128 * 4);
  uint32_t* lvseq = (uint32_t*)alloc((size_t)NE * 4);
  // pkRaw (25.6 MB) aliases embA+embB: dead before k_emb0 writes embA
  char* unionAB = (char*)alloc((size_t)NE * 16);
  int4* pkRaw = (int4*)unionAB;
  float* embA = (float*)unionAB;                           // 12.8 MB
  float* embB = (float*)(unionAB + (size_t)NN * DD * 4);   // 12.8 MB
  int2* pk0 = (int2*)alloc((size_t)NE * 8);
  int2* pk1 = (int2*)alloc((size_t)CAP1 * 8);
  int2* pk2 = (int2*)alloc((size_t)CAP2 * 8);
  int2* pk3 = (int2*)alloc((size_t)CAP3 * 8);
  float* order0 = (float*)alloc(NN * 4);
  float* order1 = (float*)alloc(NN * 4);
  float* order2 = (float*)alloc(NN * 4);
  float* embS = (float*)alloc((size_t)NN * DD * 4);
  float* num1 = (float*)alloc(NN * 4);
  float* num2 = (float*)alloc(NN * 4);
  float* numS = (float*)alloc(NN * 4);
  unsigned long long* buf = (unsigned long long*)alloc(SORTN * 8);

  uint32_t dk[3][2];
  for (int i = 0; i < 3; ++i) tf2x32(0u, 42u, 0u, (uint32_t)i, dk[i][0], dk[i][1]);

  hipMemsetAsync(zero_base, 0, zero_bytes, stream);

  k_level_count<<<(NE + 255) / 256, 256, 0, stream>>>(
      rows, dk[0][0], dk[0][1], dk[1][0], dk[1][1], dk[2][0], dk[2][1], lvseq, pcnt);

  dim3 sg(NB, 4);
  k_scan1<<<sg, SCAN_B, 0, stream>>>(pcnt, rpAll, bsumAll);
  k_scan2<<<4, 128, 0, stream>>>(bsumAll);
  k_scan3<<<sg, SCAN_B, 0, stream>>>(rpAll, bsumAll, pcnt);

  k_scatter<<<(NE + 255) / 256, 256, 0, stream>>>(rows, cols, adj, lvseq, rpAll, pkRaw);
  k_build2<<<(NN + NTB - 1) / NTB, NTB, 0, stream>>>(rpAll, pkRaw, pk0, pk1, pk2, pk3,
                                                     order0, order1, order2);

  const int* rp0 = rpAll;
  const int* rp1 = rpAll + (NN + 1);
  const int* rp2 = rpAll + 2 * (NN + 1);
  const int* rp3 = rpAll + 3 * (NN + 1);

  int gEmb = (NN * 32 + 255) / 256;
  k_emb0<<<gEmb, 256, 0, stream>>>(rp0, pk0, embeds, embA);

  // stage 1: emb cur=embA -> next=embB, num cur=order0 -> num1, sums init
  k_emb_step<<<gEmb, 256, 0, stream>>>(rp1, pk1, order0, embA, embB, embS,
                                       order0, num1, numS, 1);
  // stage 2: emb cur=embB -> next=embA, num cur=num1 -> num2, sums +=
  k_emb_step<<<gEmb, 256, 0, stream>>>(rp2, pk2, order1, embB, embA, embS,
                                       num1, num2, numS, 2);
  // stage 3: sums += only (next buffers unused dummies)
  k_emb_step<<<gEmb, 256, 0, stream>>>(rp3, pk3, order2, embA, embB, embS,
                                       num2, num1, numS, 3);

  k_final<<<(NN + 255) / 256, 256, 0, stream>>>(embeds, embS, numS, 0u, 7u, out, hist);
  k_cutoff<<<1, 1024, 0, stream>>>(hist, cnt2 + 1);
  k_collect<<<(NN + 255) / 256, 256, 0, stream>>>(out, cnt2 + 1, buf, cnt2);
  k_sort<<<1, 1024, 0, stream>>>(buf, cnt2, out + NN);
}

// Round 8
// 477.954 us; speedup vs baseline: 1.1912x; 1.0896x over previous
//
#include <hip/hip_runtime.h>
#include <stdint.h>
#include <stddef.h>

#define NN 100000
#define NE 1600000
#define DD 32
#define NCAND 1024
#define HSIZE 65536
#define SORTN 4096
#define SCAN_B 1024
#define NB ((NN + SCAN_B - 1) / SCAN_B)   // 98 blocks per scan array
#define NTB 128                            // k_build2 block size
#define KMAX 64                            // max in-LDS degree (Poisson(16) max ~45)
#define NBUK ((NN + 255) / 256)            // 391 coarse buckets of 256 rows
#define EPB 4096                           // edges per block in kA1/kA2

// capacity for per-stage packed lists (mean + huge margin)
#define CAP1 832000
#define CAP2 432000
#define CAP3 240000

// ---------------- JAX threefry2x32 (20 rounds) ----------------
__host__ __device__ inline void tf2x32(uint32_t k0, uint32_t k1, uint32_t x0, uint32_t x1,
                                       uint32_t& o0, uint32_t& o1) {
  uint32_t ks2 = k0 ^ k1 ^ 0x1BD11BDAu;
  uint32_t v0 = x0 + k0, v1 = x1 + k1;
#define TFR(r) { v0 += v1; v1 = (v1 << (r)) | (v1 >> (32 - (r))); v1 ^= v0; }
  TFR(13) TFR(15) TFR(26) TFR(6)   v0 += k1;  v1 += ks2 + 1u;
  TFR(17) TFR(29) TFR(16) TFR(24)  v0 += ks2; v1 += k0 + 2u;
  TFR(13) TFR(15) TFR(26) TFR(6)   v0 += k0;  v1 += k1 + 3u;
  TFR(17) TFR(29) TFR(16) TFR(24)  v0 += k1;  v1 += ks2 + 4u;
  TFR(13) TFR(15) TFR(26) TFR(6)   v0 += ks2; v1 += k0 + 5u;
#undef TFR
  o0 = v0; o1 = v1;
}

__device__ __forceinline__ uint32_t jax_bits32(uint32_t k0, uint32_t k1, uint32_t i) {
  uint32_t o0, o1;
  tf2x32(k0, k1, 0u, i, o0, o1);
  return o0 ^ o1;
}

__device__ __forceinline__ float bits_to_uniform(uint32_t b) {
  return __fsub_rn(__uint_as_float((b >> 9) | 0x3f800000u), 1.0f);
}

// numpy-pairwise sum of 32 floats
__device__ __forceinline__ float pairwise32(const float* x) {
  float r[8];
#pragma unroll
  for (int j = 0; j < 8; ++j) r[j] = x[j];
#pragma unroll
  for (int b = 8; b < 32; b += 8)
#pragma unroll
    for (int j = 0; j < 8; ++j) r[j] = __fadd_rn(r[j], x[b + j]);
  float a01 = __fadd_rn(r[0], r[1]), a23 = __fadd_rn(r[2], r[3]);
  float a45 = __fadd_rn(r[4], r[5]), a67 = __fadd_rn(r[6], r[7]);
  return __fadd_rn(__fadd_rn(a01, a23), __fadd_rn(a45, a67));
}

// ---------------- preprocessing: two-level binning ----------------

// bucket counts (LDS hist -> few global atomics)
__global__ __launch_bounds__(512) void kA1_count(const int* __restrict__ rows,
                                                 int* __restrict__ bucketCnt) {
  __shared__ int hist[NBUK];
  int tid = threadIdx.x;
  for (int i = tid; i < NBUK; i += 512) hist[i] = 0;
  __syncthreads();
  int e0 = blockIdx.x * EPB;
  for (int k = 0; k < 8; ++k) {
    int e = e0 + k * 512 + tid;
    if (e < NE) atomicAdd(&hist[rows[e] >> 8], 1);
  }
  __syncthreads();
  for (int i = tid; i < NBUK; i += 512)
    if (hist[i]) atomicAdd(&bucketCnt[i], hist[i]);
}

// exclusive scan of 391 bucket counts -> bucketBase[392], init bucketCursor
__global__ __launch_bounds__(512) void k_scanB(const int* __restrict__ bucketCnt,
                                               int* __restrict__ bucketBase,
                                               int* __restrict__ bucketCursor) {
  __shared__ int sb[512];
  int tid = threadIdx.x;
  int v = (tid < NBUK) ? bucketCnt[tid] : 0;
  sb[tid] = v;
  __syncthreads();
  for (int off = 1; off < 512; off <<= 1) {
    int x = (tid >= off) ? sb[tid - off] : 0;
    __syncthreads();
    sb[tid] += x;
    __syncthreads();
  }
  if (tid < NBUK) {
    int ex = sb[tid] - v;
    bucketBase[tid] = ex;
    bucketCursor[tid] = ex;
  }
  if (tid == NBUK - 1) bucketBase[NBUK] = sb[tid];
}

// threefry levels + binned scatter: payload {col, adj_bits, (eid<<2)|lv, row}
// writes grouped per (block,bucket) -> consecutive addresses -> filled lines
__global__ __launch_bounds__(512) void kA2_bin(
    const int* __restrict__ rows, const int* __restrict__ cols,
    const float* __restrict__ adj,
    uint32_t k00, uint32_t k01, uint32_t k10, uint32_t k11,
    uint32_t k20, uint32_t k21,
    int* __restrict__ bucketCursor, int4* __restrict__ pkBin) {
  __shared__ int hist[NBUK];
  __shared__ int base[NBUK];
  __shared__ uint8_t lvs[EPB];
  int tid = threadIdx.x;
  for (int i = tid; i < NBUK; i += 512) hist[i] = 0;
  __syncthreads();
  int e0 = blockIdx.x * EPB;
  for (int k = 0; k < 8; ++k) {
    int e = e0 + k * 512 + tid;
    int lv = 0;
    if (e < NE) {
      float u0 = bits_to_uniform(jax_bits32(k00, k01, (uint32_t)e));
      float u1 = bits_to_uniform(jax_bits32(k10, k11, (uint32_t)e));
      float u2 = bits_to_uniform(jax_bits32(k20, k21, (uint32_t)e));
      float kp0 = floorf(__fadd_rn(u0, 0.5f));
      float kp1 = floorf(__fadd_rn(u1, 0.25f));
      float kp2 = floorf(__fadd_rn(u2, 0.125f));
      if (kp0 != 0.0f) { lv = 1; if (kp1 != 0.0f) { lv = 2; if (kp2 != 0.0f) lv = 3; } }
      atomicAdd(&hist[rows[e] >> 8], 1);
    }
    lvs[k * 512 + tid] = (uint8_t)lv;
  }
  __syncthreads();
  for (int i = tid; i < NBUK; i += 512) {
    int h = hist[i];
    base[i] = (h > 0) ? atomicAdd(&bucketCursor[i], h) : 0;
  }
  __syncthreads();
  for (int i = tid; i < NBUK; i += 512) hist[i] = 0;
  __syncthreads();
  for (int k = 0; k < 8; ++k) {
    int e = e0 + k * 512 + tid;
    if (e < NE) {
      int r = rows[e];
      int b = r >> 8;
      int rank = atomicAdd(&hist[b], 1);
      int lv = (int)lvs[k * 512 + tid];
      pkBin[base[b] + rank] = make_int4(cols[e], __float_as_int(adj[e]), (e << 2) | lv, r);
    }
  }
}

// per-bucket row grouping in LDS; writes row-grouped pkOrd (L2-local window)
// and packed per-row per-stage counts pcnt (coalesced).
__global__ __launch_bounds__(512) void kB_group(
    const int* __restrict__ bucketBase, const int4* __restrict__ pkBin,
    int4* __restrict__ pkOrd, unsigned long long* __restrict__ pcnt) {
  __shared__ unsigned long long cnt64[256];
  __shared__ int sb[256];
  __shared__ int cur[256];
  int b = blockIdx.x, tid = threadIdx.x;
  int s = bucketBase[b], t = bucketBase[b + 1];
  int r0 = b << 8;
  int nr = NN - r0; if (nr > 256) nr = 256;
  if (tid < 256) { cnt64[tid] = 0ull; cur[tid] = 0; }
  __syncthreads();
  for (int i = s + tid; i < t; i += 512) {
    int4 p = pkBin[i];
    int lr = p.w - r0;
    int lv = p.z & 3;
    unsigned long long add = 1ull;
    if (lv >= 1) add |= 1ull << 16;
    if (lv >= 2) add |= 1ull << 32;
    if (lv >= 3) add |= 1ull << 48;
    atomicAdd(&cnt64[lr], add);
  }
  __syncthreads();
  if (tid < nr) pcnt[r0 + tid] = cnt64[tid];
  if (tid < 256) sb[tid] = (int)(cnt64[tid] & 0xFFFFull);
  __syncthreads();
  for (int off = 1; off < 256; off <<= 1) {
    int v = (tid < 256 && tid >= off) ? sb[tid - off] : 0;
    __syncthreads();
    if (tid < 256) sb[tid] += v;
    __syncthreads();
  }
  for (int i = s + tid; i < t; i += 512) {
    int4 p = pkBin[i];
    int lr = p.w - r0;
    int start = sb[lr] - (int)(cnt64[lr] & 0xFFFFull);  // exclusive
    int rank = atomicAdd(&cur[lr], 1);
    pkOrd[s + start + rank] = p;
  }
}

// ---------------- global 4-way scans over pcnt fields ----------------
__global__ void k_scan1(const unsigned long long* __restrict__ pcnt, int* __restrict__ rpAll,
                        int* __restrict__ bsumAll) {
  __shared__ int s[SCAN_B];
  int a = blockIdx.y;
  int* rp = rpAll + (size_t)a * (NN + 1);
  int gid = blockIdx.x * SCAN_B + threadIdx.x;
  int v = (gid < NN) ? (int)((pcnt[gid] >> (16 * a)) & 0xFFFFull) : 0;
  s[threadIdx.x] = v;
  __syncthreads();
  for (int off = 1; off < SCAN_B; off <<= 1) {
    int t = (threadIdx.x >= off) ? s[threadIdx.x - off] : 0;
    __syncthreads();
    s[threadIdx.x] += t;
    __syncthreads();
  }
  if (gid < NN) rp[gid] = s[threadIdx.x] - v;  // exclusive
  if (threadIdx.x == SCAN_B - 1) bsumAll[a * 128 + blockIdx.x] = s[threadIdx.x];
}

__global__ void k_scan2(int* __restrict__ bsumAll) {
  __shared__ int s[128];
  int* bsum = bsumAll + blockIdx.x * 128;
  int t = threadIdx.x;
  int v = (t < NB) ? bsum[t] : 0;
  s[t] = v;
  __syncthreads();
  for (int off = 1; off < 128; off <<= 1) {
    int x = (t >= off) ? s[t - off] : 0;
    __syncthreads();
    s[t] += x;
    __syncthreads();
  }
  if (t < NB) bsum[t] = s[t] - v;  // exclusive
}

__global__ void k_scan3(int* __restrict__ rpAll, const int* __restrict__ bsumAll,
                        const unsigned long long* __restrict__ pcnt) {
  int a = blockIdx.y;
  int* rp = rpAll + (size_t)a * (NN + 1);
  int gid = blockIdx.x * SCAN_B + threadIdx.x;
  if (gid < NN) {
    int v = rp[gid] + bsumAll[a * 128 + blockIdx.x];
    rp[gid] = v;
    if (gid == NN - 1) rp[NN] = v + (int)((pcnt[gid] >> (16 * a)) & 0xFFFFull);
  }
}

// per-row: LDS insertion sort by eid, emit packed stage lists + orders
__global__ __launch_bounds__(NTB) void k_build2(
    const int* __restrict__ rpAll, int4* __restrict__ pkOrd,
    int2* __restrict__ pk0, int2* __restrict__ pk1,
    int2* __restrict__ pk2, int2* __restrict__ pk3,
    float* __restrict__ order0, float* __restrict__ order1, float* __restrict__ order2) {
  __shared__ uint32_t K[KMAX * NTB];  // transposed: K[i*NTB + t]
  int t = threadIdx.x;
  int r = blockIdx.x * NTB + t;
  if (r >= NN) return;  // no __syncthreads below; LDS column is thread-private
  const int* rp0 = rpAll;
  const int* rp1 = rpAll + (NN + 1);
  const int* rp2 = rpAll + 2 * (NN + 1);
  const int* rp3 = rpAll + 3 * (NN + 1);
  int s = rp0[r], en = rp0[r + 1];
  int d = en - s;
  int p0 = s, p1 = rp1[r], p2 = rp2[r], p3 = rp3[r];
  float o0 = 0.0f, o1 = 0.0f, o2 = 0.0f;
  if (d <= KMAX) {
    const int4* src = pkOrd + s;
    for (int i = 0; i < d; ++i)
      K[i * NTB + t] = ((uint32_t)src[i].z << 6) | (uint32_t)i;  // (eid<<2|lv)<<6 | i
    for (int i = 1; i < d; ++i) {
      uint32_t key = K[i * NTB + t];
      int j = i - 1;
      while (j >= 0) {
        uint32_t kj = K[j * NTB + t];
        if (kj <= key) break;
        K[(j + 1) * NTB + t] = kj;
        --j;
      }
      K[(j + 1) * NTB + t] = key;
    }
    for (int i = 0; i < d; ++i) {
      uint32_t key = K[i * NTB + t];
      int idx = (int)(key & 63u);
      int lv = (int)((key >> 6) & 3u);
      int4 p = src[idx];  // L1-hot re-read
      float a = __int_as_float(p.y);
      int2 pk = make_int2(p.x, p.y);
      o0 = __fadd_rn(o0, a);
      pk0[p0++] = pk;
      if (lv >= 1) {
        o1 = __fadd_rn(o1, a);
        pk1[p1++] = pk;
        if (lv >= 2) {
          o2 = __fadd_rn(o2, a);
          pk2[p2++] = pk;
          if (lv >= 3) pk3[p3++] = pk;
        }
      }
    }
  } else {
    // effectively-never fallback: global in-place insertion sort by (eid<<2|lv)
    for (int i = s + 1; i < en; ++i) {
      int4 key = pkOrd[i];
      int j = i - 1;
      while (j >= s && pkOrd[j].z > key.z) { pkOrd[j + 1] = pkOrd[j]; --j; }
      pkOrd[j + 1] = key;
    }
    for (int i = s; i < en; ++i) {
      int4 p = pkOrd[i];
      float a = __int_as_float(p.y);
      int lv = p.z & 3;
      int2 pk = make_int2(p.x, p.y);
      o0 = __fadd_rn(o0, a);
      pk0[p0++] = pk;
      if (lv >= 1) {
        o1 = __fadd_rn(o1, a);
        pk1[p1++] = pk;
        if (lv >= 2) {
          o2 = __fadd_rn(o2, a);
          pk2[p2++] = pk;
          if (lv >= 3) pk3[p3++] = pk;
        }
      }
    }
  }
  order0[r] = o0; order1[r] = o1; order2[r] = o2;
}

// fst_emb = spmm(adj, embeds) - embeds
__global__ void k_emb0(const int* __restrict__ rp, const int2* __restrict__ pk,
                       const float* __restrict__ embeds, float* __restrict__ e0) {
  int tid = blockIdx.x * blockDim.x + threadIdx.x;
  int r = tid >> 5, d = tid & 31;
  if (r >= NN) return;
  int s = rp[r], t = rp[r + 1];
  float acc = 0.0f;
  for (int base = s; base < t; base += 32) {
    int idx = base + d;
    int2 p = (idx < t) ? pk[idx] : make_int2(0, 0);
    int m = t - base; if (m > 32) m = 32;
    for (int j = 0; j < m; ++j) {
      int c = __shfl(p.x, j, 32);
      int ab = __shfl(p.y, j, 32);
      float x = embeds[(size_t)c * DD + d];
      acc = __fadd_rn(acc, __fmul_rn(__int_as_float(ab), x));
    }
  }
  e0[(size_t)r * DD + d] = __fsub_rn(acc, embeds[(size_t)r * DD + d]);
}

// FUSED emb+num step (lane d==0 writes num outputs); modes as before
__global__ void k_emb_step(const int* __restrict__ rp, const int2* __restrict__ pk,
                           const float* __restrict__ ord, const float* __restrict__ ecur,
                           float* __restrict__ enext, float* __restrict__ esum,
                           const float* __restrict__ ncur, float* __restrict__ nnext,
                           float* __restrict__ nsum, int mode) {
  int tid = blockIdx.x * blockDim.x + threadIdx.x;
  int r = tid >> 5, d = tid & 31;
  if (r >= NN) return;
  int s = rp[r], t = rp[r + 1];
  float acc = 0.0f, accn = 0.0f;
  for (int base = s; base < t; base += 32) {
    int idx = base + d;
    int2 p = (idx < t) ? pk[idx] : make_int2(0, 0);
    int m = t - base; if (m > 32) m = 32;
    for (int j = 0; j < m; ++j) {
      int c = __shfl(p.x, j, 32);
      int ab = __shfl(p.y, j, 32);
      float av = __int_as_float(ab);
      float x = ecur[(size_t)c * DD + d];
      float xn = ncur[c];  // broadcast load
      acc = __fadd_rn(acc, __fmul_rn(av, x));
      accn = __fadd_rn(accn, __fmul_rn(av, xn));
    }
  }
  float ordv = ord[r];
  size_t idx = (size_t)r * DD + d;
  float ec = ecur[idx];
  float o = __fsub_rn(__fsub_rn(acc, ec), __fmul_rn(ordv, ec));
  if (mode != 3) enext[idx] = o;
  if (mode == 1) esum[idx] = __fadd_rn(ec, o);
  else esum[idx] = __fadd_rn(esum[idx], o);
  if (d == 0) {
    float nc = ncur[r];
    float on = __fsub_rn(__fsub_rn(accn, nc), ordv);
    if (mode != 3) nnext[r] = on;
    if (mode == 1) nsum[r] = __fadd_rn(nc, on);
    else nsum[r] = __fadd_rn(nsum[r], on);
  }
}

__global__ void k_final(const float* __restrict__ embeds, const float* __restrict__ emb_sum,
                        const float* __restrict__ num_sum, uint32_t gk0, uint32_t gk1,
                        float* __restrict__ out_scores, int* __restrict__ hist) {
  int r = blockIdx.x * blockDim.x + threadIdx.x;
  if (r >= NN) return;
  float denom = __fadd_rn(num_sum[r], 1e-8f);
  float sub[DD], em[DD], pr[DD];
  const float4* ps = (const float4*)(emb_sum + (size_t)r * DD);
  const float4* pe = (const float4*)(embeds + (size_t)r * DD);
#pragma unroll
  for (int j = 0; j < 8; ++j) {
    float4 a = ps[j], b = pe[j];
    sub[4 * j + 0] = __fdiv_rn(a.x, denom); sub[4 * j + 1] = __fdiv_rn(a.y, denom);
    sub[4 * j + 2] = __fdiv_rn(a.z, denom); sub[4 * j + 3] = __fdiv_rn(a.w, denom);
    em[4 * j + 0] = b.x; em[4 * j + 1] = b.y; em[4 * j + 2] = b.z; em[4 * j + 3] = b.w;
  }
#pragma unroll
  for (int d = 0; d < DD; ++d) pr[d] = __fmul_rn(sub[d], sub[d]);
  float n1 = fmaxf(__fsqrt_rn(pairwise32(pr)), 1e-12f);
#pragma unroll
  for (int d = 0; d < DD; ++d) pr[d] = __fmul_rn(em[d], em[d]);
  float n2 = fmaxf(__fsqrt_rn(pairwise32(pr)), 1e-12f);
#pragma unroll
  for (int d = 0; d < DD; ++d)
    pr[d] = __fmul_rn(__fdiv_rn(sub[d], n1), __fdiv_rn(em[d], n2));
  float dot = pairwise32(pr);
  float u = bits_to_uniform(jax_bits32(gk0, gk1, (uint32_t)r));
  float l1 = (float)log((double)u);
  float w = -l1;
  float l2 = (float)log((double)w);
  float g = -l2;
  float score = __fadd_rn(dot, g);
  out_scores[r] = score;
  uint32_t kb = __float_as_uint(score);
  kb = (kb & 0x80000000u) ? ~kb : (kb | 0x80000000u);
  atomicAdd(&hist[kb >> 16], 1);
}

__global__ void k_cutoff(const int* __restrict__ hist, int* __restrict__ cutoff) {
  __shared__ int psum[1024];
  int t = threadIdx.x;
  int base = HSIZE - (t + 1) * 64;
  int own = 0;
  for (int i = 0; i < 64; ++i) own += hist[base + i];
  psum[t] = own;
  __syncthreads();
  for (int off = 1; off < 1024; off <<= 1) {
    int v = (t >= off) ? psum[t - off] : 0;
    __syncthreads();
    psum[t] += v;
    __syncthreads();
  }
  int incl = psum[t];
  int prev = incl - own;
  if (incl >= NCAND && prev < NCAND) {
    int c = prev;
    int b = HSIZE - t * 64 - 1;
    while (b >= base) {
      c += hist[b];
      if (c >= NCAND) break;
      --b;
    }
    *cutoff = b;
  }
}

__global__ void k_collect(const float* __restrict__ scores, const int* __restrict__ cutoff,
                          unsigned long long* __restrict__ buf, int* __restrict__ cnt2) {
  int r = blockIdx.x * blockDim.x + threadIdx.x;
  if (r >= NN) return;
  uint32_t kb = __float_as_uint(scores[r]);
  kb = (kb & 0x80000000u) ? ~kb : (kb | 0x80000000u);
  if ((int)(kb >> 16) >= *cutoff) {
    int p = atomicAdd(cnt2, 1);
    if (p < SORTN)
      buf[p] = ((unsigned long long)kb << 32) | (uint32_t)(~(uint32_t)r);
  }
}

__global__ __launch_bounds__(1024) void k_sort(const unsigned long long* __restrict__ buf,
                                               const int* __restrict__ cnt2,
                                               float* __restrict__ out_cand) {
  __shared__ unsigned long long s[SORTN];
  int m = *cnt2;
  if (m > SORTN) m = SORTN;
  for (int i = threadIdx.x; i < SORTN; i += 1024) s[i] = (i < m) ? buf[i] : 0ull;
  __syncthreads();
  for (int k = 2; k <= SORTN; k <<= 1) {
    for (int j = k >> 1; j > 0; j >>= 1) {
      for (int i = threadIdx.x; i < SORTN; i += 1024) {
        int ixj = i ^ j;
        if (ixj > i) {
          unsigned long long a = s[i], b = s[ixj];
          bool desc = ((i & k) == 0);
          if (desc ? (a < b) : (a > b)) { s[i] = b; s[ixj] = a; }
        }
      }
      __syncthreads();
    }
  }
  for (int i = threadIdx.x; i < NCAND; i += 1024) {
    uint32_t idx = ~((uint32_t)(s[i] & 0xffffffffull));
    out_cand[i] = (float)idx;
  }
}

// ---------------- host ----------------
extern "C" void kernel_launch(void* const* d_in, const int* in_sizes, int n_in,
                              void* d_out, int out_size, void* d_ws, size_t ws_size,
                              hipStream_t stream) {
  const int* rows = (const int*)d_in[0];
  const int* cols = rows + NE;
  const float* adj = (const float*)d_in[1];
  const float* embeds = (const float*)d_in[2];
  float* out = (float*)d_out;

  char* p = (char*)d_ws;
  auto alloc = [&](size_t bytes) {
    char* q = p;
    p += (bytes + 255) & ~(size_t)255;
    return q;
  };
  // zero region: bucketCnt(NBUK) | hist(HSIZE) | cnt2(2)
  size_t zero_bytes = (size_t)(NBUK + HSIZE + 8) * 4;
  char* zero_base = (char*)alloc(zero_bytes);
  int* bucketCnt = (int*)zero_base;
  int* hist = bucketCnt + NBUK;
  int* cnt2 = hist + HSIZE;  // [0]=collect count, [1]=cutoff bin

  int* bucketBase = (int*)alloc((NBUK + 1) * 4);
  int* bucketCursor = (int*)alloc(NBUK * 4);
  unsigned long long* pcnt = (unsigned long long*)alloc((size_t)NN * 8);
  int* rpAll = (int*)alloc((size_t)4 * (NN + 1) * 4);
  int* bsumAll = (int*)alloc(4 * 128 * 4);
  // pkOrd (25.6 MB) aliases embA+embB (dead before emb0/step writes)
  char* unionAB = (char*)alloc((size_t)NE * 16);
  int4* pkOrd = (int4*)unionAB;
  float* embA = (float*)unionAB;                           // 12.8 MB
  float* embB = (float*)(unionAB + (size_t)NN * DD * 4);   // 12.8 MB
  // pkBin (25.6 MB) aliases [pk1|pk2|pk3|embS|orders|nums|buf] (all written after kB)
  size_t tail_bytes = (size_t)(CAP1 + CAP2 + CAP3) * 8 + (size_t)NN * DD * 4 +
                      (size_t)6 * NN * 4 + SORTN * 8 + 4096;
  if (tail_bytes < (size_t)NE * 16) tail_bytes = (size_t)NE * 16;
  char* unionT = (char*)alloc(tail_bytes);
  int4* pkBin = (int4*)unionT;
  char* q = unionT;
  int2* pk1 = (int2*)q; q += (size_t)CAP1 * 8;
  int2* pk2 = (int2*)q; q += (size_t)CAP2 * 8;
  int2* pk3 = (int2*)q; q += (size_t)CAP3 * 8;
  float* embS = (float*)q; q += (size_t)NN * DD * 4;
  float* order0 = (float*)q; q += (size_t)NN * 4;
  float* order1 = (float*)q; q += (size_t)NN * 4;
  float* order2 = (float*)q; q += (size_t)NN * 4;
  float* num1 = (float*)q; q += (size_t)NN * 4;
  float* num2 = (float*)q; q += (size_t)NN * 4;
  float* numS = (float*)q; q += (size_t)NN * 4;
  unsigned long long* buf = (unsigned long long*)q;
  int2* pk0 = (int2*)alloc((size_t)NE * 8);

  uint32_t dk[3][2];
  for (int i = 0; i < 3; ++i) tf2x32(0u, 42u, 0u, (uint32_t)i, dk[i][0], dk[i][1]);

  hipMemsetAsync(zero_base, 0, zero_bytes, stream);

  int gE = (NE + EPB - 1) / EPB;  // 391
  kA1_count<<<gE, 512, 0, stream>>>(rows, bucketCnt);
  k_scanB<<<1, 512, 0, stream>>>(bucketCnt, bucketBase, bucketCursor);
  kA2_bin<<<gE, 512, 0, stream>>>(rows, cols, adj, dk[0][0], dk[0][1], dk[1][0], dk[1][1],
                                  dk[2][0], dk[2][1], bucketCursor, pkBin);
  kB_group<<<NBUK, 512, 0, stream>>>(bucketBase, pkBin, pkOrd, pcnt);

  dim3 sg(NB, 4);
  k_scan1<<<sg, SCAN_B, 0, stream>>>(pcnt, rpAll, bsumAll);
  k_scan2<<<4, 128, 0, stream>>>(bsumAll);
  k_scan3<<<sg, SCAN_B, 0, stream>>>(rpAll, bsumAll, pcnt);

  k_build2<<<(NN + NTB - 1) / NTB, NTB, 0, stream>>>(rpAll, pkOrd, pk0, pk1, pk2, pk3,
                                                     order0, order1, order2);

  const int* rp0 = rpAll;
  const int* rp1 = rpAll + (NN + 1);
  const int* rp2 = rpAll + 2 * (NN + 1);
  const int* rp3 = rpAll + 3 * (NN + 1);

  int gEmb = (NN * 32 + 255) / 256;
  k_emb0<<<gEmb, 256, 0, stream>>>(rp0, pk0, embeds, embA);

  // stage 1: emb cur=embA -> next=embB, num cur=order0 -> num1, sums init
  k_emb_step<<<gEmb, 256, 0, stream>>>(rp1, pk1, order0, embA, embB, embS,
                                       order0, num1, numS, 1);
  // stage 2: emb cur=embB -> next=embA, num cur=num1 -> num2, sums +=
  k_emb_step<<<gEmb, 256, 0, stream>>>(rp2, pk2, order1, embB, embA, embS,
                                       num1, num2, numS, 2);
  // stage 3: sums += only
  k_emb_step<<<gEmb, 256, 0, stream>>>(rp3, pk3, order2, embA, embB, embS,
                                       num2, num1, numS, 3);

  k_final<<<(NN + 255) / 256, 256, 0, stream>>>(embeds, embS, numS, 0u, 7u, out, hist);
  k_cutoff<<<1, 1024, 0, stream>>>(hist, cnt2 + 1);
  k_collect<<<(NN + 255) / 256, 256, 0, stream>>>(out, cnt2 + 1, buf, cnt2);
  k_sort<<<1, 1024, 0, stream>>>(buf, cnt2, out + NN);
}